// Round 1
// baseline (468.375 us; speedup 1.0000x reference)
//
#include <hip/hip_runtime.h>

#define THREADS 256

typedef float v4f __attribute__((ext_vector_type(4)));
typedef int   v2i __attribute__((ext_vector_type(2)));

// ---------------- CSR build ----------------

// counts only (no ke: scatter re-derives positions from running cursors)
__global__ __launch_bounds__(THREADS) void k_hist(const int* __restrict__ tgt,
                                                  int* __restrict__ cnt, int E) {
    int e = blockIdx.x * THREADS + threadIdx.x;
    if (e < E) atomicAdd(&cnt[tgt[e]], 1);
}

__global__ __launch_bounds__(THREADS) void k_scan_partial(const int* __restrict__ cnt,
                                                          int* __restrict__ bsum, int N) {
    __shared__ int lds[THREADS];
    int base = blockIdx.x * 1024 + threadIdx.x * 4;
    int s = 0;
    #pragma unroll
    for (int k = 0; k < 4; ++k) { int i = base + k; if (i < N) s += cnt[i]; }
    lds[threadIdx.x] = s; __syncthreads();
    for (int off = THREADS / 2; off > 0; off >>= 1) {
        if (threadIdx.x < off) lds[threadIdx.x] += lds[threadIdx.x + off];
        __syncthreads();
    }
    if (threadIdx.x == 0) bsum[blockIdx.x] = lds[0];
}

__global__ __launch_bounds__(1024) void k_scan_bsum(int* __restrict__ bsum, int NB) {
    __shared__ int lds[1024];
    int t = threadIdx.x;
    int v = (t < NB) ? bsum[t] : 0;
    lds[t] = v; __syncthreads();
    for (int off = 1; off < 1024; off <<= 1) {
        int x = (t >= off) ? lds[t - off] : 0;
        __syncthreads();
        lds[t] += x;
        __syncthreads();
    }
    if (t < NB) bsum[t] = lds[t] - v;   // exclusive
}

// writes rowptr AND re-initializes cnt[i] = rowptr[i] (running cursor for scatter)
__global__ __launch_bounds__(THREADS) void k_scan_final(int* __restrict__ cnt,
                                                        const int* __restrict__ bsum,
                                                        int* __restrict__ rowptr,
                                                        int N, int E) {
    __shared__ int lds[THREADS];
    int base = blockIdx.x * 1024 + threadIdx.x * 4;
    int v[4]; int local = 0;
    #pragma unroll
    for (int k = 0; k < 4; ++k) {
        int i = base + k;
        v[k] = (i < N) ? cnt[i] : 0;
        local += v[k];
    }
    lds[threadIdx.x] = local; __syncthreads();
    for (int off = 1; off < THREADS; off <<= 1) {
        int x = (threadIdx.x >= off) ? lds[threadIdx.x - off] : 0;
        __syncthreads();
        lds[threadIdx.x] += x;
        __syncthreads();
    }
    int p = lds[threadIdx.x] - local + bsum[blockIdx.x];
    #pragma unroll
    for (int k = 0; k < 4; ++k) {
        int i = base + k;
        if (i < N) { rowptr[i] = p; cnt[i] = p; p += v[k]; }
    }
    if (blockIdx.x == 0 && threadIdx.x == 0) rowptr[N] = E;
}

// ---------------- node table transpose: [N][32] -> [N][8]{f0,x,y,z} ----------------
// makes the per-edge node gather in k_agg3 a single aligned 16B load per lane

__global__ __launch_bounds__(THREADS) void k_ntrans(const float* __restrict__ node,
                                                    float* __restrict__ nodeT, int NT8) {
    int t = blockIdx.x * THREADS + threadIdx.x;   // t = n*8 + i
    if (t >= NT8) return;
    int n = t >> 3, i = t & 7;
    const float* nr = node + (size_t)n * 32;
    v4f v;
    v[0] = nr[i];
    v[1] = nr[8 + 3*i + 0];
    v[2] = nr[8 + 3*i + 1];
    v[3] = nr[8 + 3*i + 2];
    *(v4f*)(nodeT + (size_t)t * 4) = v;
}

// ---------------- scatter only (e, src) into CSR order (8B per edge) ----------------
// Replaces the 64B payload scatter: random writes shrink 104MB -> 13MB; all per-edge
// data (sh0/sh1/sh2 = 57.6MB, nodeT = 12.8MB) is gathered in k_agg3 from L3.

__global__ __launch_bounds__(THREADS) void k_scatter2(const int* __restrict__ eidx,
                                                      int* __restrict__ cursor,
                                                      int* __restrict__ col2, int E) {
    int e = blockIdx.x * THREADS + threadIdx.x;
    if (e >= E) return;
    int src = eidx[e];
    int tgt = eidx[E + e];
    int pos = atomicAdd(&cursor[tgt], 1);
    v2i v; v[0] = e; v[1] = src;
    *(v2i*)(col2 + 2*(size_t)pos) = v;
}

// ---------------- fused aggregation in pre-W space + per-node postmix ----------------
// 8 threads per node; thread i = input channel i. 32 nodes per block.
// 1-deep software pipeline over ALL gathers: col2 two ahead, sh/node one ahead.

#define ACC_STRIDE 15   // 14 used +1 pad to break LDS bank conflicts

__global__ __launch_bounds__(THREADS) void k_agg3(const float* __restrict__ nodeT,
                                                  const int*   __restrict__ rowptr,
                                                  const int*   __restrict__ col2,
                                                  const float* __restrict__ sh0,
                                                  const float* __restrict__ sh1,
                                                  const float* __restrict__ sh2,
                                                  const float* __restrict__ W,
                                                  float*       __restrict__ out, int N) {
    __shared__ float sW[384];
    __shared__ float sAcc[32 * 8 * ACC_STRIDE];
    for (int t = threadIdx.x; t < 384; t += THREADS) sW[t] = W[t];
    __syncthreads();

    constexpr float IS3  = 0.57735026918962576f;
    constexpr float IS6  = 0.40824829046386302f;
    constexpr float IS10 = 0.31622776601683794f;
    constexpr float IS30 = 0.18257418583505536f;

    const int nodeSlot = threadIdx.x >> 3;
    const int i        = threadIdx.x & 7;
    const int n        = blockIdx.x * 32 + nodeSlot;

    float a[14];
    #pragma unroll
    for (int k = 0; k < 14; ++k) a[k] = 0.f;

    if (n < N) {
        const int jbeg = rowptr[n];
        const int jend = rowptr[n + 1];

        if (jbeg < jend) {
            const int jlast = jend - 1;

            // prologue: edge j, and (e,src) for edge j+1
            v2i ec = __builtin_nontemporal_load((const v2i*)(col2 + 2*(size_t)jbeg));
            {
            }
            const int e0 = ec[0];
            float s  = sh0[e0];
            const float* up = sh1 + 3*(size_t)e0;
            float u0 = up[0], u1 = up[1], u2 = up[2];
            const float* qp = sh2 + 5*(size_t)e0;
            float q0 = qp[0], q1 = qp[1], q2 = qp[2], q3 = qp[3], q4 = qp[4];
            v4f nf = *(const v4f*)(nodeT + ((size_t)ec[1] * 8 + i) * 4);

            int jn1 = (jbeg + 1 < jend) ? jbeg + 1 : jlast;
            v2i ecn = __builtin_nontemporal_load((const v2i*)(col2 + 2*(size_t)jn1));

            for (int j = jbeg; j < jend; ++j) {
                // issue gathers for edge j+1 (clamped on last iter; harmless L1 hit)
                const int en = ecn[0];
                const float ns = sh0[en];
                const float* nup = sh1 + 3*(size_t)en;
                const float nu0 = nup[0], nu1 = nup[1], nu2 = nup[2];
                const float* nqp = sh2 + 5*(size_t)en;
                const float nq0 = nqp[0], nq1 = nqp[1], nq2 = nqp[2],
                            nq3 = nqp[3], nq4 = nqp[4];
                const v4f nnf = *(const v4f*)(nodeT + ((size_t)ecn[1] * 8 + i) * 4);
                const int jn2 = (j + 2 < jend) ? j + 2 : jlast;
                const v2i ec2 = __builtin_nontemporal_load((const v2i*)(col2 + 2*(size_t)jn2));

                // compute with current (loads issued one iteration ago)
                const float f0 = nf[0], x = nf[1], y = nf[2], z = nf[3];

                const float Q00 = -q2*IS30 - q4*IS10;
                const float Q01 =  q1*IS10;
                const float Q02 =  q0*IS10;
                const float Q11 =  2.0f*q2*IS30;
                const float Q12 =  q3*IS10;
                const float Q22 = -q2*IS30 + q4*IS10;

                a[0]  += s * f0;                       // c0
                a[1]  += u0*x + u1*y + u2*z;           // c3 (pre IS3)
                a[2]  += s * x;                        // c1 (pre IS3)
                a[3]  += s * y;
                a[4]  += s * z;
                a[5]  += f0 * u0;                      // c2 (pre IS3)
                a[6]  += f0 * u1;
                a[7]  += f0 * u2;
                a[8]  += u1*z - u2*y;                  // c4 (pre IS6)
                a[9]  += u2*x - u0*z;
                a[10] += u0*y - u1*x;
                a[11] += Q00*x + Q01*y + Q02*z;        // c5
                a[12] += Q01*x + Q11*y + Q12*z;
                a[13] += Q02*x + Q12*y + Q22*z;

                // rotate pipeline
                s = ns; u0 = nu0; u1 = nu1; u2 = nu2;
                q0 = nq0; q1 = nq1; q2 = nq2; q3 = nq3; q4 = nq4;
                nf = nnf; ecn = ec2;
            }
        }
    }

    // fold norms (linear, once per node)
    #pragma unroll
    for (int k = 1; k < 8; ++k) a[k] *= IS3;
    #pragma unroll
    for (int k = 8; k < 11; ++k) a[k] *= IS6;

    float* myAcc = &sAcc[(nodeSlot * 8 + i) * ACC_STRIDE];
    #pragma unroll
    for (int k = 0; k < 14; ++k) myAcc[k] = a[k];
    __syncthreads();

    if (n < N) {
        const int o = i;
        float o0 = 0.f, ox = 0.f, oy = 0.f, oz = 0.f;
        #pragma unroll
        for (int ii = 0; ii < 8; ++ii) {
            const float* A = &sAcc[(nodeSlot * 8 + ii) * ACC_STRIDE];
            const float w0 = sW[  0 + ii*8 + o];
            const float w1 = sW[ 64 + ii*8 + o];
            const float w2 = sW[128 + ii*8 + o];
            const float w3 = sW[192 + ii*8 + o];
            const float w4 = sW[256 + ii*8 + o];
            const float w5 = sW[320 + ii*8 + o];
            o0 += w0*A[0]  + w3*A[1];
            ox += w1*A[2]  + w2*A[5] + w4*A[8]  + w5*A[11];
            oy += w1*A[3]  + w2*A[6] + w4*A[9]  + w5*A[12];
            oz += w1*A[4]  + w2*A[7] + w4*A[10] + w5*A[13];
        }
        float* orow = out + (size_t)n * 32;
        orow[o]         = o0;
        orow[8 + 3*o+0] = ox;
        orow[8 + 3*o+1] = oy;
        orow[8 + 3*o+2] = oz;
    }
}

// ---------------- fallback: round-1 atomic kernel ----------------

__global__ __launch_bounds__(THREADS) void msg_kernel_atomic(
    const float* __restrict__ node,
    const int*   __restrict__ eidx,
    const float* __restrict__ sh0,
    const float* __restrict__ sh1,
    const float* __restrict__ sh2,
    const float* __restrict__ W,
    float*       __restrict__ out,
    int E)
{
    __shared__ float sW[384];
    for (int t = threadIdx.x; t < 384; t += THREADS) sW[t] = W[t];
    __syncthreads();

    int e = blockIdx.x * THREADS + threadIdx.x;
    if (e >= E) return;

    constexpr float IS3  = 0.57735026918962576f;
    constexpr float IS6  = 0.40824829046386302f;
    constexpr float IS10 = 0.31622776601683794f;
    constexpr float IS30 = 0.18257418583505536f;

    const int src = eidx[e];
    const int tgt = eidx[E + e];

    const float s  = sh0[e];
    const float u0 = sh1[3*e+0], u1 = sh1[3*e+1], u2 = sh1[3*e+2];
    const float q0 = sh2[5*e+0], q1 = sh2[5*e+1], q2 = sh2[5*e+2],
                q3 = sh2[5*e+3], q4 = sh2[5*e+4];

    const float Q00 = -q2*IS30 - q4*IS10;
    const float Q01 =  q1*IS10;
    const float Q02 =  q0*IS10;
    const float Q11 =  2.0f*q2*IS30;
    const float Q12 =  q3*IS10;
    const float Q22 = -q2*IS30 + q4*IS10;

    float f[32];
    {
        const float4* nr = (const float4*)(node + (size_t)src * 32);
        #pragma unroll
        for (int i = 0; i < 8; ++i) {
            float4 v = nr[i];
            f[4*i+0]=v.x; f[4*i+1]=v.y; f[4*i+2]=v.z; f[4*i+3]=v.w;
        }
    }

    float msg[32];
    #pragma unroll
    for (int j = 0; j < 32; ++j) msg[j] = 0.0f;

    const float s13 = s * IS3;

    #pragma unroll
    for (int i = 0; i < 8; ++i) {
        const float f0i = f[i];
        const float x = f[8+3*i+0], y = f[8+3*i+1], z = f[8+3*i+2];
        const float c0  = s * f0i;
        const float c3  = IS3 * (u0*x + u1*y + u2*z);
        const float p2  = IS3 * f0i;
        const float c1x = s13*x, c1y = s13*y, c1z = s13*z;
        const float c2x = p2*u0, c2y = p2*u1, c2z = p2*u2;
        const float c4x = IS6*(u1*z - u2*y);
        const float c4y = IS6*(u2*x - u0*z);
        const float c4z = IS6*(u0*y - u1*x);
        const float c5x = Q00*x + Q01*y + Q02*z;
        const float c5y = Q01*x + Q11*y + Q12*z;
        const float c5z = Q02*x + Q12*y + Q22*z;

        float wr[6][8];
        #pragma unroll
        for (int c = 0; c < 6; ++c) {
            float4 aa = *(const float4*)&sW[c*64 + i*8 + 0];
            float4 bb = *(const float4*)&sW[c*64 + i*8 + 4];
            wr[c][0]=aa.x; wr[c][1]=aa.y; wr[c][2]=aa.z; wr[c][3]=aa.w;
            wr[c][4]=bb.x; wr[c][5]=bb.y; wr[c][6]=bb.z; wr[c][7]=bb.w;
        }

        #pragma unroll
        for (int o = 0; o < 8; ++o) {
            msg[o] += wr[0][o]*c0 + wr[3][o]*c3;
            msg[8+3*o+0] += wr[1][o]*c1x + wr[2][o]*c2x + wr[4][o]*c4x + wr[5][o]*c5x;
            msg[8+3*o+1] += wr[1][o]*c1y + wr[2][o]*c2y + wr[4][o]*c4y + wr[5][o]*c5y;
            msg[8+3*o+2] += wr[1][o]*c1z + wr[2][o]*c2z + wr[4][o]*c4z + wr[5][o]*c5z;
        }
    }

    float* orow = out + (size_t)tgt * 32;
    #pragma unroll
    for (int j = 0; j < 32; ++j) unsafeAtomicAdd(orow + j, msg[j]);
}

// ---------------- host ----------------

extern "C" void kernel_launch(void* const* d_in, const int* in_sizes, int n_in,
                              void* d_out, int out_size, void* d_ws, size_t ws_size,
                              hipStream_t stream) {
    const float* node = (const float*)d_in[0];
    const int*   eidx = (const int*)d_in[1];
    const float* sh0  = (const float*)d_in[2];
    const float* sh1  = (const float*)d_in[3];
    const float* sh2  = (const float*)d_in[4];
    const float* W    = (const float*)d_in[5];
    float* out = (float*)d_out;

    const int E = in_sizes[2];          // sh0 has E elements
    const int N = in_sizes[0] / 32;     // node_irreps is [N, 32]
    const int NB = (N + 1023) / 1024;

    // ws layout (words): rowptr[N+1] | cnt[N] | bsum[1024] | (align16B) col2[2E] | (align16B) nodeT[32N]
    size_t off = 0;
    size_t off_rowptr = off; off += (size_t)N + 1;
    size_t off_cnt    = off; off += (size_t)N;
    size_t off_bsum   = off; off += 1024;
    off = (off + 3) & ~(size_t)3;
    size_t off_col2   = off; off += 2 * (size_t)E;
    off = (off + 3) & ~(size_t)3;
    size_t off_nodeT  = off; off += 32 * (size_t)N;
    size_t need = off * sizeof(float);

    if (ws_size >= need && NB <= 1024) {
        int* wsI    = (int*)d_ws;
        int* rowptr = wsI + off_rowptr;
        int* cnt    = wsI + off_cnt;
        int* bsum   = wsI + off_bsum;
        int* col2   = wsI + off_col2;
        float* nodeT = (float*)d_ws + off_nodeT;

        hipMemsetAsync(cnt, 0, (size_t)N * sizeof(int), stream);

        k_hist<<<(E + THREADS - 1) / THREADS, THREADS, 0, stream>>>(eidx + E, cnt, E);
        k_ntrans<<<(8 * N + THREADS - 1) / THREADS, THREADS, 0, stream>>>(node, nodeT, 8 * N);
        k_scan_partial<<<NB, THREADS, 0, stream>>>(cnt, bsum, N);
        k_scan_bsum<<<1, 1024, 0, stream>>>(bsum, NB);
        k_scan_final<<<NB, THREADS, 0, stream>>>(cnt, bsum, rowptr, N, E);
        k_scatter2<<<(E + THREADS - 1) / THREADS, THREADS, 0, stream>>>(eidx, cnt, col2, E);

        k_agg3<<<(N + 31) / 32, THREADS, 0, stream>>>(nodeT, rowptr, col2,
                                                      sh0, sh1, sh2, W, out, N);
    } else {
        hipMemsetAsync(d_out, 0, (size_t)out_size * sizeof(float), stream);
        msg_kernel_atomic<<<(E + THREADS - 1) / THREADS, THREADS, 0, stream>>>(
            node, eidx, sh0, sh1, sh2, W, out, E);
    }
}

// Round 2
// 424.234 us; speedup vs baseline: 1.1040x; 1.1040x over previous
//
#include <hip/hip_runtime.h>

#define THREADS 256

typedef float v4f __attribute__((ext_vector_type(4)));

// ---------------- CSR build ----------------

// variant A: counts + per-target rank (atomic return value) -> no 2nd atomic pass
__global__ __launch_bounds__(THREADS) void k_hist2(const int* __restrict__ tgt,
                                                   int* __restrict__ cnt,
                                                   int* __restrict__ ke, int E) {
    int e = blockIdx.x * THREADS + threadIdx.x;
    if (e < E) ke[e] = atomicAdd(&cnt[tgt[e]], 1);
}

// variant B: counts only (saves ke ws when workspace is tight)
__global__ __launch_bounds__(THREADS) void k_hist(const int* __restrict__ tgt,
                                                  int* __restrict__ cnt, int E) {
    int e = blockIdx.x * THREADS + threadIdx.x;
    if (e < E) atomicAdd(&cnt[tgt[e]], 1);
}

__global__ __launch_bounds__(THREADS) void k_scan_partial(const int* __restrict__ cnt,
                                                          int* __restrict__ bsum, int N) {
    __shared__ int lds[THREADS];
    int base = blockIdx.x * 1024 + threadIdx.x * 4;
    int s = 0;
    #pragma unroll
    for (int k = 0; k < 4; ++k) { int i = base + k; if (i < N) s += cnt[i]; }
    lds[threadIdx.x] = s; __syncthreads();
    for (int off = THREADS / 2; off > 0; off >>= 1) {
        if (threadIdx.x < off) lds[threadIdx.x] += lds[threadIdx.x + off];
        __syncthreads();
    }
    if (threadIdx.x == 0) bsum[blockIdx.x] = lds[0];
}

__global__ __launch_bounds__(1024) void k_scan_bsum(int* __restrict__ bsum, int NB) {
    __shared__ int lds[1024];
    int t = threadIdx.x;
    int v = (t < NB) ? bsum[t] : 0;
    lds[t] = v; __syncthreads();
    for (int off = 1; off < 1024; off <<= 1) {
        int x = (t >= off) ? lds[t - off] : 0;
        __syncthreads();
        lds[t] += x;
        __syncthreads();
    }
    if (t < NB) bsum[t] = lds[t] - v;   // exclusive
}

// writes rowptr AND re-initializes cnt[i] = rowptr[i] (running cursor, variant B)
__global__ __launch_bounds__(THREADS) void k_scan_final(int* __restrict__ cnt,
                                                        const int* __restrict__ bsum,
                                                        int* __restrict__ rowptr,
                                                        int N, int E) {
    __shared__ int lds[THREADS];
    int base = blockIdx.x * 1024 + threadIdx.x * 4;
    int v[4]; int local = 0;
    #pragma unroll
    for (int k = 0; k < 4; ++k) {
        int i = base + k;
        v[k] = (i < N) ? cnt[i] : 0;
        local += v[k];
    }
    lds[threadIdx.x] = local; __syncthreads();
    for (int off = 1; off < THREADS; off <<= 1) {
        int x = (threadIdx.x >= off) ? lds[threadIdx.x - off] : 0;
        __syncthreads();
        lds[threadIdx.x] += x;
        __syncthreads();
    }
    int p = lds[threadIdx.x] - local + bsum[blockIdx.x];
    #pragma unroll
    for (int k = 0; k < 4; ++k) {
        int i = base + k;
        if (i < N) { rowptr[i] = p; cnt[i] = p; p += v[k]; }
    }
    if (blockIdx.x == 0 && threadIdx.x == 0) rowptr[N] = E;
}

// ---------------- pack (edge order, sequential) + col scatter (4B random) ----------
// pack row (16 floats, 64B aligned): [s,u0,u1,u2 | Q00,Q01,Q02,Q11 | Q12,Q22,0,0 | 0..]
// Q precomputed once per edge (was redundantly computed by 8 lanes in agg).
// Sequential full-line plain stores (L2 merges the 4x16B into one line writeback).
// col[pos]=e is a 4B random write into 6.4MB -> per-XCD L2 slice 0.8MB, lines
// accumulate all 16 entries before writeback.

__global__ __launch_bounds__(THREADS) void k_pack(const int* __restrict__ eidx,
                                                  const int* __restrict__ ke,     // null => atomic
                                                  const int* __restrict__ rowptr,
                                                  int* __restrict__ cursor,
                                                  int* __restrict__ col,
                                                  const float* __restrict__ sh0,
                                                  const float* __restrict__ sh1,
                                                  const float* __restrict__ sh2,
                                                  float* __restrict__ pack,
                                                  int E) {
    int e = blockIdx.x * THREADS + threadIdx.x;
    if (e >= E) return;

    constexpr float IS10 = 0.31622776601683794f;
    constexpr float IS30 = 0.18257418583505536f;

    const int tgt = eidx[E + e];
    int pos;
    if (ke) pos = rowptr[tgt] + ke[e];
    else    pos = atomicAdd(&cursor[tgt], 1);
    col[pos] = e;

    const float s  = __builtin_nontemporal_load(&sh0[e]);
    const float u0 = __builtin_nontemporal_load(&sh1[3*e+0]);
    const float u1 = __builtin_nontemporal_load(&sh1[3*e+1]);
    const float u2 = __builtin_nontemporal_load(&sh1[3*e+2]);
    const float q0 = __builtin_nontemporal_load(&sh2[5*e+0]);
    const float q1 = __builtin_nontemporal_load(&sh2[5*e+1]);
    const float q2 = __builtin_nontemporal_load(&sh2[5*e+2]);
    const float q3 = __builtin_nontemporal_load(&sh2[5*e+3]);
    const float q4 = __builtin_nontemporal_load(&sh2[5*e+4]);

    const float Q00 = -q2*IS30 - q4*IS10;
    const float Q01 =  q1*IS10;
    const float Q02 =  q0*IS10;
    const float Q11 =  2.0f*q2*IS30;
    const float Q12 =  q3*IS10;
    const float Q22 = -q2*IS30 + q4*IS10;

    float4* pr = (float4*)(pack + (size_t)e * 16);
    pr[0] = make_float4(s, u0, u1, u2);
    pr[1] = make_float4(Q00, Q01, Q02, Q11);
    pr[2] = make_float4(Q12, Q22, 0.f, 0.f);
    pr[3] = make_float4(0.f, 0.f, 0.f, 0.f);   // full 64B line, one touch
}

// ---------------- fused aggregation in pre-W space + per-node postmix ----------------
// 8 threads per node; thread i = input channel i. 32 nodes per block.
// Per edge: ONE aligned 64B random read (pack, nt) + esrc 4B (L2-resident, fetched in
// PARALLEL with pack so node-row loads never wait on the pack line) + node row (L2-hot).
// 1-deep pipeline on pack/node; col/esrc fetched 2-ahead.

#define ACC_STRIDE 15   // 14 used +1 pad to break LDS bank conflicts

__global__ __launch_bounds__(THREADS) void k_agg5(const float* __restrict__ node,
                                                  const int*   __restrict__ rowptr,
                                                  const int*   __restrict__ col,
                                                  const int*   __restrict__ esrc,  // eidx row 0
                                                  const float* __restrict__ pack,
                                                  const float* __restrict__ W,
                                                  float*       __restrict__ out, int N) {
    __shared__ float sW[384];
    __shared__ float sAcc[32 * 8 * ACC_STRIDE];
    for (int t = threadIdx.x; t < 384; t += THREADS) sW[t] = W[t];
    __syncthreads();

    constexpr float IS3  = 0.57735026918962576f;
    constexpr float IS6  = 0.40824829046386302f;

    const int nodeSlot = threadIdx.x >> 3;
    const int i        = threadIdx.x & 7;
    const int n        = blockIdx.x * 32 + nodeSlot;

    float a[14];
    #pragma unroll
    for (int k = 0; k < 14; ++k) a[k] = 0.f;

    if (n < N) {
        const int jbeg = rowptr[n];
        const int jend = rowptr[n + 1];

        if (jbeg < jend) {
            const int jlast = jend - 1;

            // prologue: edge jbeg fully, then (e,src) for jbeg+1
            const int e0 = __builtin_nontemporal_load(&col[jbeg]);
            const int s0 = esrc[e0];
            const v4f* pp = (const v4f*)(pack + (size_t)e0 * 16);
            v4f c0 = __builtin_nontemporal_load(pp + 0);
            v4f c1 = __builtin_nontemporal_load(pp + 1);
            v4f c2 = __builtin_nontemporal_load(pp + 2);
            const float* nr0 = node + (size_t)s0 * 32;
            float f0 = nr0[i];
            float x  = nr0[8 + 3*i + 0];
            float y  = nr0[8 + 3*i + 1];
            float z  = nr0[8 + 3*i + 2];

            const int j1 = (jbeg + 1 < jend) ? jbeg + 1 : jlast;
            int eA = __builtin_nontemporal_load(&col[j1]);
            int sA = esrc[eA];

            for (int j = jbeg; j < jend; ++j) {
                // issue gathers for edge j+1 (independent: pack by eA, node by sA)
                const v4f* pn = (const v4f*)(pack + (size_t)eA * 16);
                const v4f n0 = __builtin_nontemporal_load(pn + 0);
                const v4f n1 = __builtin_nontemporal_load(pn + 1);
                const v4f n2 = __builtin_nontemporal_load(pn + 2);
                const float* nrn = node + (size_t)sA * 32;
                const float nf0 = nrn[i];
                const float nx  = nrn[8 + 3*i + 0];
                const float ny  = nrn[8 + 3*i + 1];
                const float nz  = nrn[8 + 3*i + 2];
                // fetch (e,src) for edge j+2 (clamped; harmless repeat on tail)
                const int j2 = (j + 2 < jend) ? j + 2 : jlast;
                const int eB = __builtin_nontemporal_load(&col[j2]);
                const int sB = esrc[eB];

                // compute edge j (all operands loaded >= one iteration ago)
                const float s  = c0[0], u0 = c0[1], u1 = c0[2], u2 = c0[3];
                const float Q00 = c1[0], Q01 = c1[1], Q02 = c1[2], Q11 = c1[3];
                const float Q12 = c2[0], Q22 = c2[1];

                a[0]  += s * f0;                       // c0
                a[1]  += u0*x + u1*y + u2*z;           // c3 (pre IS3)
                a[2]  += s * x;                        // c1 (pre IS3)
                a[3]  += s * y;
                a[4]  += s * z;
                a[5]  += f0 * u0;                      // c2 (pre IS3)
                a[6]  += f0 * u1;
                a[7]  += f0 * u2;
                a[8]  += u1*z - u2*y;                  // c4 (pre IS6)
                a[9]  += u2*x - u0*z;
                a[10] += u0*y - u1*x;
                a[11] += Q00*x + Q01*y + Q02*z;        // c5
                a[12] += Q01*x + Q11*y + Q12*z;
                a[13] += Q02*x + Q12*y + Q22*z;

                // rotate pipeline
                c0 = n0; c1 = n1; c2 = n2;
                f0 = nf0; x = nx; y = ny; z = nz;
                eA = eB; sA = sB;
            }
        }
    }

    // fold norms (linear, once per node)
    #pragma unroll
    for (int k = 1; k < 8; ++k) a[k] *= IS3;
    #pragma unroll
    for (int k = 8; k < 11; ++k) a[k] *= IS6;

    float* myAcc = &sAcc[(nodeSlot * 8 + i) * ACC_STRIDE];
    #pragma unroll
    for (int k = 0; k < 14; ++k) myAcc[k] = a[k];
    __syncthreads();

    if (n < N) {
        const int o = i;
        float o0 = 0.f, ox = 0.f, oy = 0.f, oz = 0.f;
        #pragma unroll
        for (int ii = 0; ii < 8; ++ii) {
            const float* A = &sAcc[(nodeSlot * 8 + ii) * ACC_STRIDE];
            const float w0 = sW[  0 + ii*8 + o];
            const float w1 = sW[ 64 + ii*8 + o];
            const float w2 = sW[128 + ii*8 + o];
            const float w3 = sW[192 + ii*8 + o];
            const float w4 = sW[256 + ii*8 + o];
            const float w5 = sW[320 + ii*8 + o];
            o0 += w0*A[0]  + w3*A[1];
            ox += w1*A[2]  + w2*A[5] + w4*A[8]  + w5*A[11];
            oy += w1*A[3]  + w2*A[6] + w4*A[9]  + w5*A[12];
            oz += w1*A[4]  + w2*A[7] + w4*A[10] + w5*A[13];
        }
        float* orow = out + (size_t)n * 32;
        orow[o]         = o0;
        orow[8 + 3*o+0] = ox;
        orow[8 + 3*o+1] = oy;
        orow[8 + 3*o+2] = oz;
    }
}

// ---------------- fallback: round-1 atomic kernel ----------------

__global__ __launch_bounds__(THREADS) void msg_kernel_atomic(
    const float* __restrict__ node,
    const int*   __restrict__ eidx,
    const float* __restrict__ sh0,
    const float* __restrict__ sh1,
    const float* __restrict__ sh2,
    const float* __restrict__ W,
    float*       __restrict__ out,
    int E)
{
    __shared__ float sW[384];
    for (int t = threadIdx.x; t < 384; t += THREADS) sW[t] = W[t];
    __syncthreads();

    int e = blockIdx.x * THREADS + threadIdx.x;
    if (e >= E) return;

    constexpr float IS3  = 0.57735026918962576f;
    constexpr float IS6  = 0.40824829046386302f;
    constexpr float IS10 = 0.31622776601683794f;
    constexpr float IS30 = 0.18257418583505536f;

    const int src = eidx[e];
    const int tgt = eidx[E + e];

    const float s  = sh0[e];
    const float u0 = sh1[3*e+0], u1 = sh1[3*e+1], u2 = sh1[3*e+2];
    const float q0 = sh2[5*e+0], q1 = sh2[5*e+1], q2 = sh2[5*e+2],
                q3 = sh2[5*e+3], q4 = sh2[5*e+4];

    const float Q00 = -q2*IS30 - q4*IS10;
    const float Q01 =  q1*IS10;
    const float Q02 =  q0*IS10;
    const float Q11 =  2.0f*q2*IS30;
    const float Q12 =  q3*IS10;
    const float Q22 = -q2*IS30 + q4*IS10;

    float f[32];
    {
        const float4* nr = (const float4*)(node + (size_t)src * 32);
        #pragma unroll
        for (int i = 0; i < 8; ++i) {
            float4 v = nr[i];
            f[4*i+0]=v.x; f[4*i+1]=v.y; f[4*i+2]=v.z; f[4*i+3]=v.w;
        }
    }

    float msg[32];
    #pragma unroll
    for (int j = 0; j < 32; ++j) msg[j] = 0.0f;

    const float s13 = s * IS3;

    #pragma unroll
    for (int i = 0; i < 8; ++i) {
        const float f0i = f[i];
        const float x = f[8+3*i+0], y = f[8+3*i+1], z = f[8+3*i+2];
        const float c0  = s * f0i;
        const float c3  = IS3 * (u0*x + u1*y + u2*z);
        const float p2  = IS3 * f0i;
        const float c1x = s13*x, c1y = s13*y, c1z = s13*z;
        const float c2x = p2*u0, c2y = p2*u1, c2z = p2*u2;
        const float c4x = IS6*(u1*z - u2*y);
        const float c4y = IS6*(u2*x - u0*z);
        const float c4z = IS6*(u0*y - u1*x);
        const float c5x = Q00*x + Q01*y + Q02*z;
        const float c5y = Q01*x + Q11*y + Q12*z;
        const float c5z = Q02*x + Q12*y + Q22*z;

        float wr[6][8];
        #pragma unroll
        for (int c = 0; c < 6; ++c) {
            float4 aa = *(const float4*)&sW[c*64 + i*8 + 0];
            float4 bb = *(const float4*)&sW[c*64 + i*8 + 4];
            wr[c][0]=aa.x; wr[c][1]=aa.y; wr[c][2]=aa.z; wr[c][3]=aa.w;
            wr[c][4]=bb.x; wr[c][5]=bb.y; wr[c][6]=bb.z; wr[c][7]=bb.w;
        }

        #pragma unroll
        for (int o = 0; o < 8; ++o) {
            msg[o] += wr[0][o]*c0 + wr[3][o]*c3;
            msg[8+3*o+0] += wr[1][o]*c1x + wr[2][o]*c2x + wr[4][o]*c4x + wr[5][o]*c5x;
            msg[8+3*o+1] += wr[1][o]*c1y + wr[2][o]*c2y + wr[4][o]*c4y + wr[5][o]*c5y;
            msg[8+3*o+2] += wr[1][o]*c1z + wr[2][o]*c2z + wr[4][o]*c4z + wr[5][o]*c5z;
        }
    }

    float* orow = out + (size_t)tgt * 32;
    #pragma unroll
    for (int j = 0; j < 32; ++j) unsafeAtomicAdd(orow + j, msg[j]);
}

// ---------------- host ----------------

extern "C" void kernel_launch(void* const* d_in, const int* in_sizes, int n_in,
                              void* d_out, int out_size, void* d_ws, size_t ws_size,
                              hipStream_t stream) {
    const float* node = (const float*)d_in[0];
    const int*   eidx = (const int*)d_in[1];
    const float* sh0  = (const float*)d_in[2];
    const float* sh1  = (const float*)d_in[3];
    const float* sh2  = (const float*)d_in[4];
    const float* W    = (const float*)d_in[5];
    float* out = (float*)d_out;

    const int E = in_sizes[2];          // sh0 has E elements
    const int N = in_sizes[0] / 32;     // node_irreps is [N, 32]
    const int NB = (N + 1023) / 1024;

    // ws layout (words), variant A (ke) / variant B (atomic cursor):
    //   rowptr[N+1] | cnt[N] | bsum[1024] | [ke[E]] | col[E] | (align 64B) pack[16E]
    size_t base_w = (size_t)(N + 1) + N + 1024;
    size_t intA_w = base_w + (size_t)E + (size_t)E;   // ke + col
    size_t intB_w = base_w + (size_t)E;               // col only
    size_t packA_off = (intA_w + 15) & ~(size_t)15;
    size_t packB_off = (intB_w + 15) & ~(size_t)15;
    size_t needA = (packA_off + (size_t)E * 16) * sizeof(float);
    size_t needB = (packB_off + (size_t)E * 16) * sizeof(float);

    const int gridE = (E + THREADS - 1) / THREADS;

    if (ws_size >= needB && NB <= 1024) {
        const bool useKe = (ws_size >= needA);

        int* wsI    = (int*)d_ws;
        int* rowptr = wsI;
        int* cnt    = rowptr + (N + 1);
        int* bsum   = cnt + N;
        int* ke     = useKe ? (bsum + 1024) : nullptr;
        int* col    = useKe ? (ke + E) : (bsum + 1024);
        float* pack = (float*)d_ws + (useKe ? packA_off : packB_off);

        hipMemsetAsync(cnt, 0, (size_t)N * sizeof(int), stream);

        if (useKe)
            k_hist2<<<gridE, THREADS, 0, stream>>>(eidx + E, cnt, ke, E);
        else
            k_hist<<<gridE, THREADS, 0, stream>>>(eidx + E, cnt, E);

        k_scan_partial<<<NB, THREADS, 0, stream>>>(cnt, bsum, N);
        k_scan_bsum<<<1, 1024, 0, stream>>>(bsum, NB);
        k_scan_final<<<NB, THREADS, 0, stream>>>(cnt, bsum, rowptr, N, E);

        k_pack<<<gridE, THREADS, 0, stream>>>(eidx, ke, rowptr, cnt, col,
                                              sh0, sh1, sh2, pack, E);

        k_agg5<<<(N + 31) / 32, THREADS, 0, stream>>>(node, rowptr, col, eidx,
                                                      pack, W, out, N);
    } else {
        hipMemsetAsync(d_out, 0, (size_t)out_size * sizeof(float), stream);
        msg_kernel_atomic<<<gridE, THREADS, 0, stream>>>(
            node, eidx, sh0, sh1, sh2, W, out, E);
    }
}

// Round 3
// 360.838 us; speedup vs baseline: 1.2980x; 1.1757x over previous
//
#include <hip/hip_runtime.h>

#define THREADS 256

typedef float v4f __attribute__((ext_vector_type(4)));

// ---------------- CSR build ----------------

// counts only; scatter derives positions from atomic running cursors
__global__ __launch_bounds__(THREADS) void k_hist(const int* __restrict__ tgt,
                                                  int* __restrict__ cnt, int E) {
    int e = blockIdx.x * THREADS + threadIdx.x;
    if (e < E) atomicAdd(&cnt[tgt[e]], 1);
}

__global__ __launch_bounds__(THREADS) void k_scan_partial(const int* __restrict__ cnt,
                                                          int* __restrict__ bsum, int N) {
    __shared__ int lds[THREADS];
    int base = blockIdx.x * 1024 + threadIdx.x * 4;
    int s = 0;
    #pragma unroll
    for (int k = 0; k < 4; ++k) { int i = base + k; if (i < N) s += cnt[i]; }
    lds[threadIdx.x] = s; __syncthreads();
    for (int off = THREADS / 2; off > 0; off >>= 1) {
        if (threadIdx.x < off) lds[threadIdx.x] += lds[threadIdx.x + off];
        __syncthreads();
    }
    if (threadIdx.x == 0) bsum[blockIdx.x] = lds[0];
}

__global__ __launch_bounds__(1024) void k_scan_bsum(int* __restrict__ bsum, int NB) {
    __shared__ int lds[1024];
    int t = threadIdx.x;
    int v = (t < NB) ? bsum[t] : 0;
    lds[t] = v; __syncthreads();
    for (int off = 1; off < 1024; off <<= 1) {
        int x = (t >= off) ? lds[t - off] : 0;
        __syncthreads();
        lds[t] += x;
        __syncthreads();
    }
    if (t < NB) bsum[t] = lds[t] - v;   // exclusive
}

// writes rowptr AND re-initializes cnt[i] = rowptr[i] (running cursor for scatter)
__global__ __launch_bounds__(THREADS) void k_scan_final(int* __restrict__ cnt,
                                                        const int* __restrict__ bsum,
                                                        int* __restrict__ rowptr,
                                                        int N, int E) {
    __shared__ int lds[THREADS];
    int base = blockIdx.x * 1024 + threadIdx.x * 4;
    int v[4]; int local = 0;
    #pragma unroll
    for (int k = 0; k < 4; ++k) {
        int i = base + k;
        v[k] = (i < N) ? cnt[i] : 0;
        local += v[k];
    }
    lds[threadIdx.x] = local; __syncthreads();
    for (int off = 1; off < THREADS; off <<= 1) {
        int x = (threadIdx.x >= off) ? lds[threadIdx.x - off] : 0;
        __syncthreads();
        lds[threadIdx.x] += x;
        __syncthreads();
    }
    int p = lds[threadIdx.x] - local + bsum[blockIdx.x];
    #pragma unroll
    for (int k = 0; k < 4; ++k) {
        int i = base + k;
        if (i < N) { rowptr[i] = p; cnt[i] = p; p += v[k]; }
    }
    if (blockIdx.x == 0 && threadIdx.x == 0) rowptr[N] = E;
}

// ---------------- scatter payload into CSR order (full 64B rows) ----------------
// payload row (16 floats, 64B): [s,u0,u1,u2 | Q00,Q01,Q02,Q11 | Q12,Q22,src,0 | 0,0,0,0]
// Random 64B writes pay NO line-fill (R0 measured: WRITE_SIZE == payload bytes exactly);
// the agg then reads the payload as a perfectly-sequential nt stream (line-perfect).
// Plain stores: L2 merges the 4x16B into one 64B-sector writeback (R9: nt stores here
// bypassed the merge -> 2.4x write traffic).

__global__ __launch_bounds__(THREADS) void k_scatter3(const int* __restrict__ eidx,
                                                      int* __restrict__ cursor,
                                                      const float* __restrict__ sh0,
                                                      const float* __restrict__ sh1,
                                                      const float* __restrict__ sh2,
                                                      float* __restrict__ pay,
                                                      int E) {
    int e = blockIdx.x * THREADS + threadIdx.x;
    if (e >= E) return;

    constexpr float IS10 = 0.31622776601683794f;
    constexpr float IS30 = 0.18257418583505536f;

    const int src = eidx[e];
    const int tgt = eidx[E + e];
    const int pos = atomicAdd(&cursor[tgt], 1);

    // sequential streams; nontemporal so 58MB of sh doesn't evict node/cnt from L2
    const float s  = __builtin_nontemporal_load(&sh0[e]);
    const float u0 = __builtin_nontemporal_load(&sh1[3*e+0]);
    const float u1 = __builtin_nontemporal_load(&sh1[3*e+1]);
    const float u2 = __builtin_nontemporal_load(&sh1[3*e+2]);
    const float q0 = __builtin_nontemporal_load(&sh2[5*e+0]);
    const float q1 = __builtin_nontemporal_load(&sh2[5*e+1]);
    const float q2 = __builtin_nontemporal_load(&sh2[5*e+2]);
    const float q3 = __builtin_nontemporal_load(&sh2[5*e+3]);
    const float q4 = __builtin_nontemporal_load(&sh2[5*e+4]);

    const float Q00 = -q2*IS30 - q4*IS10;
    const float Q01 =  q1*IS10;
    const float Q02 =  q0*IS10;
    const float Q11 =  2.0f*q2*IS30;
    const float Q12 =  q3*IS10;
    const float Q22 = -q2*IS30 + q4*IS10;

    float4* pr = (float4*)(pay + (size_t)pos * 16);
    pr[0] = make_float4(s, u0, u1, u2);
    pr[1] = make_float4(Q00, Q01, Q02, Q11);
    pr[2] = make_float4(Q12, Q22, __int_as_float(src), 0.f);
    pr[3] = make_float4(0.f, 0.f, 0.f, 0.f);   // full 64B line, one touch
}

// ---------------- fused aggregation in pre-W space + per-node postmix ----------------
// 8 threads per node; thread i = input channel i. 32 nodes per block.
// Payload streamed SEQUENTIALLY (nt, 2-deep prefetch); node row (one aligned 128B
// line, L2-hot 12.8MB table) prefetched 1-deep using src from the 2-deep payload.
// Every gather has >= one full iteration of compute as latency cover.

#define ACC_STRIDE 15   // 14 used +1 pad to break LDS bank conflicts

__global__ __launch_bounds__(THREADS) void k_agg6(const float* __restrict__ node,
                                                  const int*   __restrict__ rowptr,
                                                  const float* __restrict__ pay,
                                                  const float* __restrict__ W,
                                                  float*       __restrict__ out, int N) {
    __shared__ float sW[384];
    __shared__ float sAcc[32 * 8 * ACC_STRIDE];
    for (int t = threadIdx.x; t < 384; t += THREADS) sW[t] = W[t];
    __syncthreads();

    constexpr float IS3  = 0.57735026918962576f;
    constexpr float IS6  = 0.40824829046386302f;

    const int nodeSlot = threadIdx.x >> 3;
    const int i        = threadIdx.x & 7;
    const int n        = blockIdx.x * 32 + nodeSlot;

    float a[14];
    #pragma unroll
    for (int k = 0; k < 14; ++k) a[k] = 0.f;

    if (n < N) {
        const int jbeg = rowptr[n];
        const int jend = rowptr[n + 1];

        if (jbeg < jend) {
            const int jlast = jend - 1;

            // prologue: payload j, node row j, payload j+1 in flight
            const v4f* p0 = (const v4f*)(pay + (size_t)jbeg * 16);
            v4f c0 = __builtin_nontemporal_load(p0 + 0);
            v4f c1 = __builtin_nontemporal_load(p0 + 1);
            v4f c2 = __builtin_nontemporal_load(p0 + 2);
            const int s0 = __float_as_int(c2[2]);
            const float* nr0 = node + (size_t)s0 * 32;
            float f0 = nr0[i];
            float x  = nr0[8 + 3*i + 0];
            float y  = nr0[8 + 3*i + 1];
            float z  = nr0[8 + 3*i + 2];

            const int j1 = (jbeg + 1 < jend) ? jbeg + 1 : jlast;
            const v4f* p1 = (const v4f*)(pay + (size_t)j1 * 16);
            v4f d0 = __builtin_nontemporal_load(p1 + 0);
            v4f d1 = __builtin_nontemporal_load(p1 + 1);
            v4f d2 = __builtin_nontemporal_load(p1 + 2);

            for (int j = jbeg; j < jend; ++j) {
                // payload j+1 arrived (issued last iter): extract src, launch node j+1
                const int sn = __float_as_int(d2[2]);
                const float* nrn = node + (size_t)sn * 32;
                const float nf0 = nrn[i];
                const float nx  = nrn[8 + 3*i + 0];
                const float ny  = nrn[8 + 3*i + 1];
                const float nz  = nrn[8 + 3*i + 2];
                // launch payload j+2 (clamped; harmless repeat on tail)
                const int j2 = (j + 2 < jend) ? j + 2 : jlast;
                const v4f* p2 = (const v4f*)(pay + (size_t)j2 * 16);
                const v4f e0 = __builtin_nontemporal_load(p2 + 0);
                const v4f e1 = __builtin_nontemporal_load(p2 + 1);
                const v4f e2 = __builtin_nontemporal_load(p2 + 2);

                // compute edge j (payload + node row both loaded >= 1 iter ago)
                const float s  = c0[0], u0 = c0[1], u1 = c0[2], u2 = c0[3];
                const float Q00 = c1[0], Q01 = c1[1], Q02 = c1[2], Q11 = c1[3];
                const float Q12 = c2[0], Q22 = c2[1];

                a[0]  += s * f0;                       // c0
                a[1]  += u0*x + u1*y + u2*z;           // c3 (pre IS3)
                a[2]  += s * x;                        // c1 (pre IS3)
                a[3]  += s * y;
                a[4]  += s * z;
                a[5]  += f0 * u0;                      // c2 (pre IS3)
                a[6]  += f0 * u1;
                a[7]  += f0 * u2;
                a[8]  += u1*z - u2*y;                  // c4 (pre IS6)
                a[9]  += u2*x - u0*z;
                a[10] += u0*y - u1*x;
                a[11] += Q00*x + Q01*y + Q02*z;        // c5
                a[12] += Q01*x + Q11*y + Q12*z;
                a[13] += Q02*x + Q12*y + Q22*z;

                // rotate pipeline
                c0 = d0; c1 = d1; c2 = d2;
                d0 = e0; d1 = e1; d2 = e2;
                f0 = nf0; x = nx; y = ny; z = nz;
            }
        }
    }

    // fold norms (linear, once per node)
    #pragma unroll
    for (int k = 1; k < 8; ++k) a[k] *= IS3;
    #pragma unroll
    for (int k = 8; k < 11; ++k) a[k] *= IS6;

    float* myAcc = &sAcc[(nodeSlot * 8 + i) * ACC_STRIDE];
    #pragma unroll
    for (int k = 0; k < 14; ++k) myAcc[k] = a[k];
    __syncthreads();

    if (n < N) {
        const int o = i;
        float o0 = 0.f, ox = 0.f, oy = 0.f, oz = 0.f;
        #pragma unroll
        for (int ii = 0; ii < 8; ++ii) {
            const float* A = &sAcc[(nodeSlot * 8 + ii) * ACC_STRIDE];
            const float w0 = sW[  0 + ii*8 + o];
            const float w1 = sW[ 64 + ii*8 + o];
            const float w2 = sW[128 + ii*8 + o];
            const float w3 = sW[192 + ii*8 + o];
            const float w4 = sW[256 + ii*8 + o];
            const float w5 = sW[320 + ii*8 + o];
            o0 += w0*A[0]  + w3*A[1];
            ox += w1*A[2]  + w2*A[5] + w4*A[8]  + w5*A[11];
            oy += w1*A[3]  + w2*A[6] + w4*A[9]  + w5*A[12];
            oz += w1*A[4]  + w2*A[7] + w4*A[10] + w5*A[13];
        }
        float* orow = out + (size_t)n * 32;
        orow[o]         = o0;
        orow[8 + 3*o+0] = ox;
        orow[8 + 3*o+1] = oy;
        orow[8 + 3*o+2] = oz;
    }
}

// ---------------- fallback: round-1 atomic kernel ----------------

__global__ __launch_bounds__(THREADS) void msg_kernel_atomic(
    const float* __restrict__ node,
    const int*   __restrict__ eidx,
    const float* __restrict__ sh0,
    const float* __restrict__ sh1,
    const float* __restrict__ sh2,
    const float* __restrict__ W,
    float*       __restrict__ out,
    int E)
{
    __shared__ float sW[384];
    for (int t = threadIdx.x; t < 384; t += THREADS) sW[t] = W[t];
    __syncthreads();

    int e = blockIdx.x * THREADS + threadIdx.x;
    if (e >= E) return;

    constexpr float IS3  = 0.57735026918962576f;
    constexpr float IS6  = 0.40824829046386302f;
    constexpr float IS10 = 0.31622776601683794f;
    constexpr float IS30 = 0.18257418583505536f;

    const int src = eidx[e];
    const int tgt = eidx[E + e];

    const float s  = sh0[e];
    const float u0 = sh1[3*e+0], u1 = sh1[3*e+1], u2 = sh1[3*e+2];
    const float q0 = sh2[5*e+0], q1 = sh2[5*e+1], q2 = sh2[5*e+2],
                q3 = sh2[5*e+3], q4 = sh2[5*e+4];

    const float Q00 = -q2*IS30 - q4*IS10;
    const float Q01 =  q1*IS10;
    const float Q02 =  q0*IS10;
    const float Q11 =  2.0f*q2*IS30;
    const float Q12 =  q3*IS10;
    const float Q22 = -q2*IS30 + q4*IS10;

    float f[32];
    {
        const float4* nr = (const float4*)(node + (size_t)src * 32);
        #pragma unroll
        for (int i = 0; i < 8; ++i) {
            float4 v = nr[i];
            f[4*i+0]=v.x; f[4*i+1]=v.y; f[4*i+2]=v.z; f[4*i+3]=v.w;
        }
    }

    float msg[32];
    #pragma unroll
    for (int j = 0; j < 32; ++j) msg[j] = 0.0f;

    const float s13 = s * IS3;

    #pragma unroll
    for (int i = 0; i < 8; ++i) {
        const float f0i = f[i];
        const float x = f[8+3*i+0], y = f[8+3*i+1], z = f[8+3*i+2];
        const float c0  = s * f0i;
        const float c3  = IS3 * (u0*x + u1*y + u2*z);
        const float p2  = IS3 * f0i;
        const float c1x = s13*x, c1y = s13*y, c1z = s13*z;
        const float c2x = p2*u0, c2y = p2*u1, c2z = p2*u2;
        const float c4x = IS6*(u1*z - u2*y);
        const float c4y = IS6*(u2*x - u0*z);
        const float c4z = IS6*(u0*y - u1*x);
        const float c5x = Q00*x + Q01*y + Q02*z;
        const float c5y = Q01*x + Q11*y + Q12*z;
        const float c5z = Q02*x + Q12*y + Q22*z;

        float wr[6][8];
        #pragma unroll
        for (int c = 0; c < 6; ++c) {
            float4 aa = *(const float4*)&sW[c*64 + i*8 + 0];
            float4 bb = *(const float4*)&sW[c*64 + i*8 + 4];
            wr[c][0]=aa.x; wr[c][1]=aa.y; wr[c][2]=aa.z; wr[c][3]=aa.w;
            wr[c][4]=bb.x; wr[c][5]=bb.y; wr[c][6]=bb.z; wr[c][7]=bb.w;
        }

        #pragma unroll
        for (int o = 0; o < 8; ++o) {
            msg[o] += wr[0][o]*c0 + wr[3][o]*c3;
            msg[8+3*o+0] += wr[1][o]*c1x + wr[2][o]*c2x + wr[4][o]*c4x + wr[5][o]*c5x;
            msg[8+3*o+1] += wr[1][o]*c1y + wr[2][o]*c2y + wr[4][o]*c4y + wr[5][o]*c5y;
            msg[8+3*o+2] += wr[1][o]*c1z + wr[2][o]*c2z + wr[4][o]*c4z + wr[5][o]*c5z;
        }
    }

    float* orow = out + (size_t)tgt * 32;
    #pragma unroll
    for (int j = 0; j < 32; ++j) unsafeAtomicAdd(orow + j, msg[j]);
}

// ---------------- host ----------------

extern "C" void kernel_launch(void* const* d_in, const int* in_sizes, int n_in,
                              void* d_out, int out_size, void* d_ws, size_t ws_size,
                              hipStream_t stream) {
    const float* node = (const float*)d_in[0];
    const int*   eidx = (const int*)d_in[1];
    const float* sh0  = (const float*)d_in[2];
    const float* sh1  = (const float*)d_in[3];
    const float* sh2  = (const float*)d_in[4];
    const float* W    = (const float*)d_in[5];
    float* out = (float*)d_out;

    const int E = in_sizes[2];          // sh0 has E elements
    const int N = in_sizes[0] / 32;     // node_irreps is [N, 32]
    const int NB = (N + 1023) / 1024;

    // ws layout (words): rowptr[N+1] | cnt[N] | bsum[1024] | (align 64B) pay[16E]
    size_t int_words = (size_t)(N + 1) + N + 1024;
    size_t pay_off_w = (int_words + 15) & ~(size_t)15;       // 64B-align payload
    size_t need      = (pay_off_w + (size_t)E * 16) * sizeof(float);

    const int gridE = (E + THREADS - 1) / THREADS;

    if (ws_size >= need && NB <= 1024) {
        int* rowptr = (int*)d_ws;
        int* cnt    = rowptr + (N + 1);
        int* bsum   = cnt + N;
        float* pay  = (float*)d_ws + pay_off_w;

        hipMemsetAsync(cnt, 0, (size_t)N * sizeof(int), stream);

        k_hist<<<gridE, THREADS, 0, stream>>>(eidx + E, cnt, E);
        k_scan_partial<<<NB, THREADS, 0, stream>>>(cnt, bsum, N);
        k_scan_bsum<<<1, 1024, 0, stream>>>(bsum, NB);
        k_scan_final<<<NB, THREADS, 0, stream>>>(cnt, bsum, rowptr, N, E);

        k_scatter3<<<gridE, THREADS, 0, stream>>>(eidx, cnt, sh0, sh1, sh2, pay, E);

        k_agg6<<<(N + 31) / 32, THREADS, 0, stream>>>(node, rowptr, pay, W, out, N);
    } else {
        hipMemsetAsync(d_out, 0, (size_t)out_size * sizeof(float), stream);
        msg_kernel_atomic<<<gridE, THREADS, 0, stream>>>(
            node, eidx, sh0, sh1, sh2, W, out, E);
    }
}